// Round 10
// baseline (296.437 us; speedup 1.0000x reference)
//
#include <hip/hip_runtime.h>

#define D 64
#define GB_B 8       // b-rows per gamma block
#define MAXS 32

typedef float f32x4 __attribute__((ext_vector_type(4)));

__device__ __forceinline__ float frcp(float x)  { return __builtin_amdgcn_rcpf(x); }
__device__ __forceinline__ float fsq(float x)   { return __builtin_amdgcn_sqrtf(x); }
__device__ __forceinline__ float frsq(float x)  { return __builtin_amdgcn_rsqf(x); }

// ---------------------------------------------------------------------------
// Kernel A: gamma[b][u] = 1 - 0.01*exp(3 * (+-clip(it_norm[b] . u_norm[u])))
// (unchanged, verified R4-R9)
// ---------------------------------------------------------------------------
__global__ __launch_bounds__(256) void gamma_kernel(
        const float* __restrict__ user_emb,
        const float* __restrict__ item_emb,
        const int*   __restrict__ iids,
        const int*   __restrict__ inter,
        float*       __restrict__ gamma,
        int U, int B) {
    __shared__ float s_it[GB_B * D];     // 2 KB
    const int tid  = threadIdx.x;
    const int lane = tid & 63;
    const int w    = tid >> 6;
    const int b0   = blockIdx.y * GB_B;
    const int nb   = min(GB_B, B - b0);

    for (int bb = w; bb < nb; bb += 4) {
        const int row = iids[b0 + bb];
        const float x = item_emb[(size_t)row * D + lane];
        float ss = x * x;
        #pragma unroll
        for (int off = 32; off > 0; off >>= 1)
            ss += __shfl_xor(ss, off, 64);
        s_it[bb * D + lane] = x * frcp(fmaxf(fsq(ss), 1e-12f));
    }

    const int u  = blockIdx.x * 256 + tid;
    const int uc = (u < U) ? u : (U - 1);
    float4 uv[16];
    const float4* __restrict__ up = (const float4*)(user_emb + (size_t)uc * D);
    #pragma unroll
    for (int j = 0; j < 16; ++j) uv[j] = up[j];

    float ssq = 0.f;
    #pragma unroll
    for (int j = 0; j < 16; ++j)
        ssq += uv[j].x*uv[j].x + uv[j].y*uv[j].y + uv[j].z*uv[j].z + uv[j].w*uv[j].w;
    const float rnorm = frcp(fmaxf(fsq(ssq), 1e-12f));

    __syncthreads();

    int itv[GB_B];
    #pragma unroll
    for (int bb = 0; bb < GB_B; ++bb)
        itv[bb] = (bb < nb && u < U) ? inter[(size_t)(b0 + bb) * U + u] : 1;

    #pragma unroll
    for (int bb = 0; bb < GB_B; ++bb) {
        if (bb >= nb) break;
        const float4* __restrict__ ip = (const float4*)(s_it + bb * D);
        float d = 0.f;
        #pragma unroll
        for (int j = 0; j < 16; ++j) {
            const float4 iv = ip[j];
            d += uv[j].x*iv.x + uv[j].y*iv.y + uv[j].z*iv.z + uv[j].w*iv.w;
        }
        float score = fminf(fmaxf(d * rnorm, -1.0f), 1.0f);
        if (itv[bb] != 1) score = -score;
        const float gm = 1.0f - 0.01f * __expf(3.0f * score);
        if (u < U) gamma[(size_t)(b0 + bb) * U + u] = gm;
    }
}

// ---------------------------------------------------------------------------
// val(k, s): ap = acp_{s-1}, ac = acp_s, an = acp_{s+1}|0, bt = g*bb_s.
// Formulas identical to R5-R9 (numerics-preserving); k folds at compile time.
// ---------------------------------------------------------------------------
__device__ __forceinline__ float val_ks(int k, float ap, float ac, float an,
                                        float bt) {
    const float al = 1.0f - bt;
    if (k == 0)  return frsq(al);                          // sqrt_recip_alphas
    if (k == 1)  return ac;                                // alphas_cumprod
    if (k == 2)  return fsq(1.0f - ac);                    // sqrt_one_minus_acp
    if (k == 3)  return ap;                                // acp_prev
    if (k == 4)  return an;                                // acp_next
    if (k == 5)  return fsq(ac);                           // sqrt_acp
    if (k == 6)  return __logf(1.0f - ac);                 // log_one_minus_acp
    if (k == 7)  return frsq(ac);                          // sqrt_recip_acp
    if (k == 8)  return fsq(1.0f - ac) * frsq(ac);         // sqrt_recipm1_acp
    if (k == 9)  return bt * fsq(ap) * frcp(1.0f - ac);    // post_mean_coef1
    if (k == 10) return (1.0f - ap) * (al * frsq(al)) * frcp(1.0f - ac); // pmc2
    if (k == 11) return fsq(1.0f - ap) * frcp(fsq(1.0f - ac)); // fast_coef2
    if (k == 12) return fsq(ac) * fsq(1.0f - ap) * frcp(fsq(1.0f - ac)); // fc3
    return bt * (1.0f - ap) * frcp(1.0f - ac);             // 13: post_variance
}

// ---------------------------------------------------------------------------
// Kernel B (S compile-time): K-MAJOR order + nt stores (R8, best 137.7us).
// R10 change: DUAL-HALF — each thread owns TWO gamma positions 1024 floats
// apart; block span per (k,s) = 8 KB contiguous (two coalesced 1 KB bursts
// per wave). Halves the number of simultaneously-live write windows
// (1250x4KB -> 625x8KB) — the same lever that bought R8's +15us.
// No early return: all threads execute all barriers (guarded stores).
// ---------------------------------------------------------------------------
template<int SS>
__global__ __launch_bounds__(256) void store_kernel_t(
        const float* __restrict__ gamma,
        const float* __restrict__ base_betas,
        float*       __restrict__ out,
        size_t P) {                        // P = B*U
    __shared__ float s_bb[SS];
    if (threadIdx.x < SS) s_bb[threadIdx.x] = base_betas[threadIdx.x];
    __syncthreads();

    const size_t pA = (size_t)blockIdx.x * 2048 + (size_t)threadIdx.x * 4;
    const size_t pB = pA + 1024;
    const bool fullA = (pA + 4 <= P);
    const bool fullB = (pB + 4 <= P);

    f32x4 gA, gB;
    if (fullA) gA = *(const f32x4*)(gamma + pA);
    else for (int e = 0; e < 4; ++e) gA[e] = (pA + e < P) ? gamma[pA + e] : 1.0f;
    if (fullB) gB = *(const f32x4*)(gamma + pB);
    else for (int e = 0; e < 4; ++e) gB[e] = (pB + e < P) ? gamma[pB + e] : 1.0f;

    float bb[SS];
    #pragma unroll
    for (int s = 0; s < SS; ++s) bb[s] = s_bb[s];

    // acp history in registers: h*[0] = 1, h*[s+1] = acp_s
    f32x4 hA[SS + 1], hB[SS + 1];
    for (int e = 0; e < 4; ++e) { hA[0][e] = 1.0f; hB[0][e] = 1.0f; }
    #pragma unroll
    for (int s = 0; s < SS; ++s)
        for (int e = 0; e < 4; ++e) {
            hA[s + 1][e] = hA[s][e] * (1.0f - gA[e] * bb[s]);
            hB[s + 1][e] = hB[s][e] * (1.0f - gB[e] * bb[s]);
        }

    const size_t SBU = (size_t)SS * P;

    #pragma unroll
    for (int k = 0; k < 14; ++k) {
        #pragma unroll
        for (int s = 0; s < SS; ++s) {
            f32x4 vA, vB;
            for (int e = 0; e < 4; ++e) {
                const float anA = (s + 1 < SS) ? hA[(s + 2 <= SS) ? s + 2 : SS][e] : 0.0f;
                const float anB = (s + 1 < SS) ? hB[(s + 2 <= SS) ? s + 2 : SS][e] : 0.0f;
                vA[e] = val_ks(k, hA[s][e], hA[s + 1][e], anA, gA[e] * bb[s]);
                vB[e] = val_ks(k, hB[s][e], hB[s + 1][e], anB, gB[e] * bb[s]);
            }
            const size_t base = (size_t)k * SBU + (size_t)s * P;
            float* _pA = out + base + pA;
            float* _pB = out + base + pB;
            if (fullA) __builtin_nontemporal_store(vA, (f32x4*)_pA);
            else for (int c = 0; c < 4; ++c) if (pA + c < P) _pA[c] = vA[c];
            if (fullB) __builtin_nontemporal_store(vB, (f32x4*)_pB);
            else for (int c = 0; c < 4; ++c) if (pB + c < P) _pB[c] = vB[c];
            __builtin_amdgcn_sched_barrier(0);
            __builtin_amdgcn_s_barrier();      // block pacing within family
            __builtin_amdgcn_sched_barrier(0);
        }
    }
}

// ---------------------------------------------------------------------------
// Generic-S fallback (correctness path; test always has S=10). nt restored.
// ---------------------------------------------------------------------------
__global__ __launch_bounds__(256) void store_kernel_gen(
        const float* __restrict__ gamma,
        const float* __restrict__ base_betas,
        float*       __restrict__ out,
        int S, size_t P) {
    __shared__ float s_bb[MAXS];
    if (threadIdx.x < S) s_bb[threadIdx.x] = base_betas[threadIdx.x];
    __syncthreads();

    const size_t p = ((size_t)blockIdx.x * 256 + threadIdx.x) * 4;
    if (p >= P) return;
    const bool full = (p + 4 <= P);

    f32x4 g;
    if (full) {
        g = *(const f32x4*)(gamma + p);
    } else {
        for (int e = 0; e < 4; ++e)
            g[e] = (p + e < P) ? gamma[p + e] : 1.0f;
    }

    const size_t SBU = (size_t)S * P;
    float* __restrict__ o = out + p;

    f32x4 acp; for (int e = 0; e < 4; ++e) acp[e] = 1.0f;

    for (int s = 0; s < S; ++s) {
        const float bbs = s_bb[s];
        const float bbn = (s + 1 < S) ? s_bb[s + 1] : 0.0f;
        f32x4 aprev = acp;
        #pragma unroll
        for (int k = 0; k < 14; ++k) {
            f32x4 v;
            for (int e = 0; e < 4; ++e) {
                const float ap = aprev[e];
                const float ac = ap * (1.0f - g[e] * bbs);
                const float an = (s + 1 < S) ? ac * (1.0f - g[e] * bbn) : 0.0f;
                v[e] = val_ks(k, ap, ac, an, g[e] * bbs);
            }
            float* _p = o + (size_t)k * SBU + (size_t)s * P;
            if (full) {
                __builtin_nontemporal_store(v, (f32x4*)_p);
            } else {
                for (int _c = 0; _c < 4; ++_c)
                    if (p + _c < P) _p[_c] = v[_c];
            }
        }
        for (int e = 0; e < 4; ++e) acp[e] *= (1.0f - g[e] * bbs);
    }
}

extern "C" void kernel_launch(void* const* d_in, const int* in_sizes, int n_in,
                              void* d_out, int out_size, void* d_ws, size_t ws_size,
                              hipStream_t stream) {
    const float* user_emb   = (const float*)d_in[0];   // [U, 64]
    const float* item_emb   = (const float*)d_in[1];   // [I, 64]
    const int*   iids       = (const int*)d_in[2];     // [B]
    const int*   inter      = (const int*)d_in[3];     // [B, U]
    const float* base_betas = (const float*)d_in[4];   // [S]

    const int U = in_sizes[0] / D;
    const int B = in_sizes[2];
    const int S = in_sizes[4];

    float* out = (float*)d_out;
    const size_t P = (size_t)B * U;

    // gamma: workspace if it fits, else the acp_next[S-1] slab of out
    // (each store-kernel thread reads its gamma before any store; the k=4,
    //  s=S-1 address p is only ever written by that same thread — race-free).
    float* gamma = (ws_size >= P * sizeof(float))
                 ? (float*)d_ws
                 : out + (size_t)(5 * S - 1) * P;

    dim3 ga((U + 255) / 256, (B + GB_B - 1) / GB_B);
    gamma_kernel<<<ga, 256, 0, stream>>>(user_emb, item_emb, iids, inter,
                                         gamma, U, B);

    if (S == 10) {
        const int blocks = (int)((P + 2047) / 2048);
        store_kernel_t<10><<<blocks, 256, 0, stream>>>(gamma, base_betas,
                                                       out, P);
    } else {
        const int blocks = (int)((P / 4 + 255) / 256);
        store_kernel_gen<<<blocks, 256, 0, stream>>>(gamma, base_betas,
                                                     out, S, P);
    }
}

// Round 11
// 136.599 us; speedup vs baseline: 2.1701x; 2.1701x over previous
//
#include <hip/hip_runtime.h>

#define D 64
#define GB_B 8       // b-rows per gamma block
#define MAXS 32

typedef float f32x4 __attribute__((ext_vector_type(4)));

__device__ __forceinline__ float frcp(float x)  { return __builtin_amdgcn_rcpf(x); }
__device__ __forceinline__ float fsq(float x)   { return __builtin_amdgcn_sqrtf(x); }
__device__ __forceinline__ float frsq(float x)  { return __builtin_amdgcn_rsqf(x); }

// ---------------------------------------------------------------------------
// Kernel A: gamma[b][u] = 1 - 0.01*exp(3 * (+-clip(it_norm[b] . u_norm[u])))
// (unchanged, verified R4-R10)
// ---------------------------------------------------------------------------
__global__ __launch_bounds__(256) void gamma_kernel(
        const float* __restrict__ user_emb,
        const float* __restrict__ item_emb,
        const int*   __restrict__ iids,
        const int*   __restrict__ inter,
        float*       __restrict__ gamma,
        int U, int B) {
    __shared__ float s_it[GB_B * D];     // 2 KB
    const int tid  = threadIdx.x;
    const int lane = tid & 63;
    const int w    = tid >> 6;
    const int b0   = blockIdx.y * GB_B;
    const int nb   = min(GB_B, B - b0);

    for (int bb = w; bb < nb; bb += 4) {
        const int row = iids[b0 + bb];
        const float x = item_emb[(size_t)row * D + lane];
        float ss = x * x;
        #pragma unroll
        for (int off = 32; off > 0; off >>= 1)
            ss += __shfl_xor(ss, off, 64);
        s_it[bb * D + lane] = x * frcp(fmaxf(fsq(ss), 1e-12f));
    }

    const int u  = blockIdx.x * 256 + tid;
    const int uc = (u < U) ? u : (U - 1);
    float4 uv[16];
    const float4* __restrict__ up = (const float4*)(user_emb + (size_t)uc * D);
    #pragma unroll
    for (int j = 0; j < 16; ++j) uv[j] = up[j];

    float ssq = 0.f;
    #pragma unroll
    for (int j = 0; j < 16; ++j)
        ssq += uv[j].x*uv[j].x + uv[j].y*uv[j].y + uv[j].z*uv[j].z + uv[j].w*uv[j].w;
    const float rnorm = frcp(fmaxf(fsq(ssq), 1e-12f));

    __syncthreads();

    int itv[GB_B];
    #pragma unroll
    for (int bb = 0; bb < GB_B; ++bb)
        itv[bb] = (bb < nb && u < U) ? inter[(size_t)(b0 + bb) * U + u] : 1;

    #pragma unroll
    for (int bb = 0; bb < GB_B; ++bb) {
        if (bb >= nb) break;
        const float4* __restrict__ ip = (const float4*)(s_it + bb * D);
        float d = 0.f;
        #pragma unroll
        for (int j = 0; j < 16; ++j) {
            const float4 iv = ip[j];
            d += uv[j].x*iv.x + uv[j].y*iv.y + uv[j].z*iv.z + uv[j].w*iv.w;
        }
        float score = fminf(fmaxf(d * rnorm, -1.0f), 1.0f);
        if (itv[bb] != 1) score = -score;
        const float gm = 1.0f - 0.01f * __expf(3.0f * score);
        if (u < U) gamma[(size_t)(b0 + bb) * U + u] = gm;
    }
}

// ---------------------------------------------------------------------------
// val(k, s) from acp history: ap = acp_{s-1}, ac = acp_s, an = acp_{s+1}|0,
// bt = g*bb_s. Formulas identical to R5-R10 (numerics-preserving).
// k is a compile-time constant in the unrolled loop -> if-chain folds.
// ---------------------------------------------------------------------------
__device__ __forceinline__ float val_ks(int k, float ap, float ac, float an,
                                        float bt) {
    const float al = 1.0f - bt;
    if (k == 0)  return frsq(al);                          // sqrt_recip_alphas
    if (k == 1)  return ac;                                // alphas_cumprod
    if (k == 2)  return fsq(1.0f - ac);                    // sqrt_one_minus_acp
    if (k == 3)  return ap;                                // acp_prev
    if (k == 4)  return an;                                // acp_next
    if (k == 5)  return fsq(ac);                           // sqrt_acp
    if (k == 6)  return __logf(1.0f - ac);                 // log_one_minus_acp
    if (k == 7)  return frsq(ac);                          // sqrt_recip_acp
    if (k == 8)  return fsq(1.0f - ac) * frsq(ac);         // sqrt_recipm1_acp
    if (k == 9)  return bt * fsq(ap) * frcp(1.0f - ac);    // post_mean_coef1
    if (k == 10) return (1.0f - ap) * (al * frsq(al)) * frcp(1.0f - ac); // pmc2
    if (k == 11) return fsq(1.0f - ap) * frcp(fsq(1.0f - ac)); // fast_coef2
    if (k == 12) return fsq(ac) * fsq(1.0f - ap) * frcp(fsq(1.0f - ac)); // fc3
    return bt * (1.0f - ap) * frcp(1.0f - ac);             // 13: post_variance
}

// ---------------------------------------------------------------------------
// Kernel B (S known at compile time): K-MAJOR store order + nt stores —
// the R8 configuration, best measured 137.7 us. acp history in registers
// (S+1 f32x4, all indices compile-time). For each k family the chip sweeps
// the contiguous 51 MB region [k][0..S-1][..]: one ~5 MB active write
// window instead of 14 scattered ones. Settled A/Bs: nt > plain (R6, R9),
// window-halving regresses (R10: spills + 625-block imbalance).
// ---------------------------------------------------------------------------
template<int SS>
__global__ __launch_bounds__(256) void store_kernel_t(
        const float* __restrict__ gamma,
        const float* __restrict__ base_betas,
        float*       __restrict__ out,
        size_t P) {                        // P = B*U
    __shared__ float s_bb[SS];
    if (threadIdx.x < SS) s_bb[threadIdx.x] = base_betas[threadIdx.x];
    __syncthreads();

    const size_t p = ((size_t)blockIdx.x * 256 + threadIdx.x) * 4;
    if (p >= P) return;
    const bool full = (p + 4 <= P);

    f32x4 g;
    if (full) {
        g = *(const f32x4*)(gamma + p);
    } else {
        for (int e = 0; e < 4; ++e)
            g[e] = (p + e < P) ? gamma[p + e] : 1.0f;
    }

    float bb[SS];
    #pragma unroll
    for (int s = 0; s < SS; ++s) bb[s] = s_bb[s];

    // acp history in registers: hist[0] = 1, hist[s+1] = acp_s
    f32x4 hist[SS + 1];
    for (int e = 0; e < 4; ++e) hist[0][e] = 1.0f;
    #pragma unroll
    for (int s = 0; s < SS; ++s)
        for (int e = 0; e < 4; ++e)
            hist[s + 1][e] = hist[s][e] * (1.0f - g[e] * bb[s]);

    const size_t SBU = (size_t)SS * P;
    float* __restrict__ o = out + p;

    #pragma unroll
    for (int k = 0; k < 14; ++k) {
        #pragma unroll
        for (int s = 0; s < SS; ++s) {
            f32x4 v;
            for (int e = 0; e < 4; ++e) {
                const float ap = hist[s][e];
                const float ac = hist[s + 1][e];
                const float an = (s + 1 < SS) ? hist[(s + 2 <= SS) ? s + 2 : SS][e] : 0.0f;
                v[e] = val_ks(k, ap, ac, an, g[e] * bb[s]);
            }
            float* _p = o + (size_t)k * SBU + (size_t)s * P;
            if (full) {
                __builtin_nontemporal_store(v, (f32x4*)_p);
            } else {
                for (int _c = 0; _c < 4; ++_c)
                    if (p + _c < P) _p[_c] = v[_c];
            }
            __builtin_amdgcn_sched_barrier(0);
            __builtin_amdgcn_s_barrier();      // block pacing within family
            __builtin_amdgcn_sched_barrier(0);
        }
    }
}

// ---------------------------------------------------------------------------
// Generic-S fallback (correctness path; test always has S=10).
// ---------------------------------------------------------------------------
__global__ __launch_bounds__(256) void store_kernel_gen(
        const float* __restrict__ gamma,
        const float* __restrict__ base_betas,
        float*       __restrict__ out,
        int S, size_t P) {
    __shared__ float s_bb[MAXS];
    if (threadIdx.x < S) s_bb[threadIdx.x] = base_betas[threadIdx.x];
    __syncthreads();

    const size_t p = ((size_t)blockIdx.x * 256 + threadIdx.x) * 4;
    if (p >= P) return;
    const bool full = (p + 4 <= P);

    f32x4 g;
    if (full) {
        g = *(const f32x4*)(gamma + p);
    } else {
        for (int e = 0; e < 4; ++e)
            g[e] = (p + e < P) ? gamma[p + e] : 1.0f;
    }

    const size_t SBU = (size_t)S * P;
    float* __restrict__ o = out + p;

    f32x4 acp; for (int e = 0; e < 4; ++e) acp[e] = 1.0f;

    for (int s = 0; s < S; ++s) {
        const float bbs = s_bb[s];
        const float bbn = (s + 1 < S) ? s_bb[s + 1] : 0.0f;
        f32x4 aprev = acp;
        #pragma unroll
        for (int k = 0; k < 14; ++k) {
            f32x4 v;
            for (int e = 0; e < 4; ++e) {
                const float ap = aprev[e];
                const float ac = ap * (1.0f - g[e] * bbs);
                const float an = (s + 1 < S) ? ac * (1.0f - g[e] * bbn) : 0.0f;
                v[e] = val_ks(k, ap, ac, an, g[e] * bbs);
            }
            float* _p = o + (size_t)k * SBU + (size_t)s * P;
            if (full) {
                __builtin_nontemporal_store(v, (f32x4*)_p);
            } else {
                for (int _c = 0; _c < 4; ++_c)
                    if (p + _c < P) _p[_c] = v[_c];
            }
        }
        for (int e = 0; e < 4; ++e) acp[e] *= (1.0f - g[e] * bbs);
        __builtin_amdgcn_s_barrier();
    }
}

extern "C" void kernel_launch(void* const* d_in, const int* in_sizes, int n_in,
                              void* d_out, int out_size, void* d_ws, size_t ws_size,
                              hipStream_t stream) {
    const float* user_emb   = (const float*)d_in[0];   // [U, 64]
    const float* item_emb   = (const float*)d_in[1];   // [I, 64]
    const int*   iids       = (const int*)d_in[2];     // [B]
    const int*   inter      = (const int*)d_in[3];     // [B, U]
    const float* base_betas = (const float*)d_in[4];   // [S]

    const int U = in_sizes[0] / D;
    const int B = in_sizes[2];
    const int S = in_sizes[4];

    float* out = (float*)d_out;
    const size_t P = (size_t)B * U;

    // gamma: workspace if it fits, else the acp_next[S-1] slab of out
    // (each store-kernel thread reads gamma[p] before any store; the k=4,
    //  s=S-1 address p is only ever written by that same thread — race-free).
    float* gamma = (ws_size >= P * sizeof(float))
                 ? (float*)d_ws
                 : out + (size_t)(5 * S - 1) * P;

    dim3 ga((U + 255) / 256, (B + GB_B - 1) / GB_B);
    gamma_kernel<<<ga, 256, 0, stream>>>(user_emb, item_emb, iids, inter,
                                         gamma, U, B);

    const int blocks = (int)((P / 4 + 255) / 256);
    if (S == 10) {
        store_kernel_t<10><<<blocks, 256, 0, stream>>>(gamma, base_betas,
                                                       out, P);
    } else {
        store_kernel_gen<<<blocks, 256, 0, stream>>>(gamma, base_betas,
                                                     out, S, P);
    }
}